// Round 1
// baseline (268.834 us; speedup 1.0000x reference)
//
#include <hip/hip_runtime.h>
#include <cstdint>

// CamPoseNet: replicate JAX reference bit-faithfully.
//   qn = q/||q||; E = quaternion matrix; lam = [1e-6, -Z0, -Z1, -Z2]
//   X  = Bingham ACG rejection sample driven by jax.random (threefry2x32,
//        partitionable counter mode, fold-like split)
//   out = E^T X
// All float ops on the accept-decision path use __f*_rn intrinsics so the
// compiler cannot contract to FMA (matches XLA:CPU strict mul/add).

#define DEVI __device__ __forceinline__

DEVI uint32_t rotl32(uint32_t v, int s) { return (v << s) | (v >> (32 - s)); }

// Standard Threefry-2x32, 20 rounds (matches jax._src.prng.threefry2x32).
DEVI void tf2x32(uint32_t k0, uint32_t k1, uint32_t x0, uint32_t x1,
                 uint32_t& o0, uint32_t& o1) {
  const uint32_t kx = k0 ^ k1 ^ 0x1BD11BDAu;
  x0 += k0; x1 += k1;
#define TFR(r) x0 += x1; x1 = rotl32(x1, (r)); x1 ^= x0;
  TFR(13) TFR(15) TFR(26) TFR(6)
  x0 += k1; x1 += kx + 1u;
  TFR(17) TFR(29) TFR(16) TFR(24)
  x0 += kx; x1 += k0 + 2u;
  TFR(13) TFR(15) TFR(26) TFR(6)
  x0 += k0; x1 += k1 + 3u;
  TFR(17) TFR(29) TFR(16) TFR(24)
  x0 += k1; x1 += kx + 4u;
  TFR(13) TFR(15) TFR(26) TFR(6)
  x0 += kx; x1 += k0 + 5u;
#undef TFR
  o0 = x0; o1 = x1;
}

// XLA:CPU's Cephes-style f32 log (llvm_ir_runtime GenerateVF32Log / Eigen
// plog transcription), strict mul/add. Caller guarantees x > 0, normal.
DEVI float xla_logf_pos(float xf) {
  uint32_t bits = __float_as_uint(xf);
  float e = (float)((int)(bits >> 23) - 126);
  float m = __uint_as_float((bits & 0x007fffffu) | 0x3f000000u);  // [0.5,1)
  if (m < 0.70710678118654752440f) {
    e = __fsub_rn(e, 1.0f);
    m = __fadd_rn(__fsub_rn(m, 1.0f), m);   // (m-1)+m  == 2m-1 (exact)
  } else {
    m = __fsub_rn(m, 1.0f);
  }
  float z = __fmul_rn(m, m);
  float y = 7.0376836292e-2f;
  y = __fadd_rn(__fmul_rn(y, m), -1.1514610310e-1f);
  y = __fadd_rn(__fmul_rn(y, m),  1.1676998740e-1f);
  y = __fadd_rn(__fmul_rn(y, m), -1.2420140846e-1f);
  y = __fadd_rn(__fmul_rn(y, m),  1.4249322787e-1f);
  y = __fadd_rn(__fmul_rn(y, m), -1.6668057665e-1f);
  y = __fadd_rn(__fmul_rn(y, m),  2.0000714765e-1f);
  y = __fadd_rn(__fmul_rn(y, m), -2.4999993993e-1f);
  y = __fadd_rn(__fmul_rn(y, m),  3.3333331174e-1f);
  y = __fmul_rn(y, m);
  y = __fmul_rn(y, z);
  y = __fadd_rn(y, __fmul_rn(e, -2.12194440e-4f));
  y = __fsub_rn(y, __fmul_rn(z, 0.5f));
  float r = __fadd_rn(m, y);
  r = __fadd_rn(r, __fmul_rn(e, 0.693359375f));
  return r;
}

// XLA ElementalIrEmitter::EmitLog1p
DEVI float xla_log1pf(float v) {
  if (fabsf(v) < 1e-4f) {
    return __fmul_rn(__fadd_rn(__fmul_rn(-0.5f, v), 1.0f), v);
  }
  return xla_logf_pos(__fadd_rn(v, 1.0f));
}

// XLA ErfInv32 (Giles single-precision polynomial)
DEVI float xla_erfinvf(float x) {
  float w = -xla_log1pf(-__fmul_rn(x, x));
  float p;
  if (w < 5.0f) {
    float q = __fsub_rn(w, 2.5f);
    p = 2.81022636e-08f;
    p = __fadd_rn(__fmul_rn(p, q),  3.43273939e-07f);
    p = __fadd_rn(__fmul_rn(p, q), -3.5233877e-06f);
    p = __fadd_rn(__fmul_rn(p, q), -4.39150654e-06f);
    p = __fadd_rn(__fmul_rn(p, q),  0.00021858087f);
    p = __fadd_rn(__fmul_rn(p, q), -0.00125372503f);
    p = __fadd_rn(__fmul_rn(p, q), -0.00417768164f);
    p = __fadd_rn(__fmul_rn(p, q),  0.246640727f);
    p = __fadd_rn(__fmul_rn(p, q),  1.50140941f);
  } else {
    float q = __fsub_rn(sqrtf(w), 3.0f);
    p = -0.000200214257f;
    p = __fadd_rn(__fmul_rn(p, q),  0.000100950558f);
    p = __fadd_rn(__fmul_rn(p, q),  0.00134934322f);
    p = __fadd_rn(__fmul_rn(p, q), -0.00367342844f);
    p = __fadd_rn(__fmul_rn(p, q),  0.00573950773f);
    p = __fadd_rn(__fmul_rn(p, q), -0.0076224613f);
    p = __fadd_rn(__fmul_rn(p, q),  0.00943887047f);
    p = __fadd_rn(__fmul_rn(p, q),  1.00167406f);
    p = __fadd_rn(__fmul_rn(p, q),  2.83297682f);
  }
  return __fmul_rn(p, x);
}

// jax uniform bit->float: bitcast(bits>>9 | 1.0f) - 1.0  in [0,1)
DEVI float u01_from_bits(uint32_t bits) {
  return __fsub_rn(__uint_as_float(0x3f800000u | (bits >> 9)), 1.0f);
}

__global__ __launch_bounds__(256) void campose_kernel(
    const float* __restrict__ q, const float* __restrict__ Z,
    const int* __restrict__ seedp, float* __restrict__ out, int N) {
  int n = blockIdx.x * blockDim.x + threadIdx.x;
  if (n >= N) return;

  // lam = [1e-6, -Z0, -Z1, -Z2]; sigacginv = 1+2lam; sig = sqrt(1/sigacginv)
  float lam[4], sgi[4], sig[4];
  lam[0] = 1e-6f;
  lam[1] = -Z[n * 3 + 0];
  lam[2] = -Z[n * 3 + 1];
  lam[3] = -Z[n * 3 + 2];
#pragma unroll
  for (int j = 0; j < 4; ++j) {
    sgi[j] = __fadd_rn(1.0f, __fmul_rn(2.0f, lam[j]));
    sig[j] = sqrtf(__fdiv_rn(1.0f, sgi[j]));
  }

  // jax.random.key(seed) -> threefry key (0, seed). Uniform across threads,
  // so the key-chain threefrys below scalarize to SALU.
  uint32_t ka = 0u, kb = (uint32_t)seedp[0];

  float X0 = 0.0f, X1 = 0.0f, X2 = 0.0f, X3 = 0.0f;
  bool acc = false;
  const uint32_t base = ((uint32_t)n) * 4u;

  for (int t = 0; t < 256 && !acc; ++t) {
    // fold-like split(key, 3): subkey_i = tf(key, 0, i), pair IS the key
    uint32_t nka, nkb, s1a, s1b, s2a, s2b;
    tf2x32(ka, kb, 0u, 0u, nka, nkb);   // next carry key
    tf2x32(ka, kb, 0u, 1u, s1a, s1b);   // k1: normals
    tf2x32(ka, kb, 0u, 2u, s2a, s2b);   // k2: uniform
    ka = nka; kb = nkb;

    // yp = normal(k1,(N,4)) * sig ; partitionable bits: o0^o1 @ counter (0,f)
    float y[4];
#pragma unroll
    for (int j = 0; j < 4; ++j) {
      uint32_t o0, o1;
      tf2x32(s1a, s1b, 0u, base + (uint32_t)j, o0, o1);
      float u = u01_from_bits(o0 ^ o1);
      // uniform(lo=-0.99999994, hi=1): u*2.0f + lo, clamped below at lo
      float xin = __fadd_rn(__fmul_rn(u, 2.0f), -0.99999994f);
      xin = fmaxf(-0.99999994f, xin);
      float nv = __fmul_rn(1.41421356237309504880f, xla_erfinvf(xin));
      y[j] = __fmul_rn(nv, sig[j]);
    }

    // y /= ||y||  (sequential reduce order, as XLA reduce)
    float n2 = __fmul_rn(y[0], y[0]);
    n2 = __fadd_rn(n2, __fmul_rn(y[1], y[1]));
    n2 = __fadd_rn(n2, __fmul_rn(y[2], y[2]));
    n2 = __fadd_rn(n2, __fmul_rn(y[3], y[3]));
    float nr = sqrtf(n2);
#pragma unroll
    for (int j = 0; j < 4; ++j) y[j] = __fdiv_rn(y[j], nr);

    float y2[4];
#pragma unroll
    for (int j = 0; j < 4; ++j) y2[j] = __fmul_rn(y[j], y[j]);

    float s1 = __fmul_rn(y2[0], lam[0]);
    s1 = __fadd_rn(s1, __fmul_rn(y2[1], lam[1]));
    s1 = __fadd_rn(s1, __fmul_rn(y2[2], lam[2]));
    s1 = __fadd_rn(s1, __fmul_rn(y2[3], lam[3]));

    float s2 = __fmul_rn(y2[0], sgi[0]);
    s2 = __fadd_rn(s2, __fmul_rn(y2[1], sgi[1]));
    s2 = __fadd_rn(s2, __fmul_rn(y2[2], sgi[2]));
    s2 = __fadd_rn(s2, __fmul_rn(y2[3], sgi[3]));

    // lratio = ((-s1 - 2*ln4) + 1.5) + 2*ln(s2)
    float lr = __fsub_rn(-s1, 2.7725887298583984f);  // 2*f32(ln 4)
    lr = __fadd_rn(lr, 1.5f);
    lr = __fadd_rn(lr, __fmul_rn(2.0f, xla_logf_pos(s2)));

    // u = uniform(k2, (N,)): counter (0, n)
    uint32_t o0, o1;
    tf2x32(s2a, s2b, 0u, (uint32_t)n, o0, o1);
    float uu = u01_from_bits(o0 ^ o1);
    float lu = (uu > 0.0f) ? xla_logf_pos(uu) : -__builtin_inff();

    if (lu < lr) { acc = true; X0 = y[0]; X1 = y[1]; X2 = y[2]; X3 = y[3]; }
  }

  // qn = q/||q||; out = E^T X
  float a = q[n * 4 + 0], b = q[n * 4 + 1], c = q[n * 4 + 2], d = q[n * 4 + 3];
  float qn2 = __fmul_rn(a, a);
  qn2 = __fadd_rn(qn2, __fmul_rn(b, b));
  qn2 = __fadd_rn(qn2, __fmul_rn(c, c));
  qn2 = __fadd_rn(qn2, __fmul_rn(d, d));
  float qnr = sqrtf(qn2);
  a = __fdiv_rn(a, qnr); b = __fdiv_rn(b, qnr);
  c = __fdiv_rn(c, qnr); d = __fdiv_rn(d, qnr);

  // E rows: r1=[a,-b,-c,d] r2=[b,a,d,c] r3=[c,-d,a,-b] r4=[d,c,-b,-a]
  float o0v = __fadd_rn(__fadd_rn(__fadd_rn(__fmul_rn(a, X0), __fmul_rn(b, X1)),
                                  __fmul_rn(c, X2)), __fmul_rn(d, X3));
  float o1v = __fadd_rn(__fadd_rn(__fadd_rn(__fmul_rn(-b, X0), __fmul_rn(a, X1)),
                                  __fmul_rn(-d, X2)), __fmul_rn(c, X3));
  float o2v = __fadd_rn(__fadd_rn(__fadd_rn(__fmul_rn(-c, X0), __fmul_rn(d, X1)),
                                  __fmul_rn(a, X2)), __fmul_rn(-b, X3));
  float o3v = __fadd_rn(__fadd_rn(__fadd_rn(__fmul_rn(d, X0), __fmul_rn(c, X1)),
                                  __fmul_rn(-b, X2)), __fmul_rn(-a, X3));

  float4 o = make_float4(o0v, o1v, o2v, o3v);
  *reinterpret_cast<float4*>(out + (size_t)n * 4) = o;
}

extern "C" void kernel_launch(void* const* d_in, const int* in_sizes, int n_in,
                              void* d_out, int out_size, void* d_ws, size_t ws_size,
                              hipStream_t stream) {
  const float* q = (const float*)d_in[0];
  const float* Z = (const float*)d_in[1];
  const int* seed = (const int*)d_in[2];
  float* out = (float*)d_out;
  int N = in_sizes[0] / 4;
  int block = 256;
  int grid = (N + block - 1) / block;
  campose_kernel<<<grid, block, 0, stream>>>(q, Z, seed, out, N);
}